// Round 9
// baseline (252.348 us; speedup 1.0000x reference)
//
#include <hip/hip_runtime.h>

typedef __bf16 bf16;
typedef bf16 bf16x4 __attribute__((ext_vector_type(4)));
typedef bf16 bf16x8 __attribute__((ext_vector_type(8)));
typedef _Float16 half_t;
typedef half_t half4 __attribute__((ext_vector_type(4)));
typedef half_t half8 __attribute__((ext_vector_type(8)));
typedef float f32x4 __attribute__((ext_vector_type(4)));

#define NND 98      // landmarks
#define KNB 10      // neighbors per node
#define NH 4        // heads
#define CIN 256
#define HC 64
#define SKP 136     // S k-stride (128 + 8 pad) -> 68-dword stride, ~2-way banks (free)
#define D0R 120     // D0T row-stride (112 + 8 pad) -> 60-dword stride, ~2-way banks
#define S_HALFS (64 * SKP)         // per item: 8704 halfs
#define S_BYTES (2 * S_HALFS * 2)  // 34816 B
#define D0_HALFS (64 * D0R)        // 7680 halfs per item
#define XA_TILE (7 * 8 * 64 * 8)   // bf16 elems per batch item in xa

// workspace layout
#define WP_OFF   0
#define WP_BYTES 262144                      // 8*8*4*64*8 bf16
#define G2A_OFF  (WP_OFF + WP_BYTES)
#define G2A_BYTES (NH * 28 * 64 * 8 * 2)     // frag-packed A_off (K=128), f16: 114688
#define DIAG_OFF (G2A_OFF + G2A_BYTES)
#define DIAG_BYTES 2048                      // NH*112 f32 (padded)
#define XA_OFF   (DIAG_OFF + DIAG_BYTES)

__device__ __forceinline__ bf16x8 load_a8(const float* p) {
  f32x4 u = *(const f32x4*)p;
  f32x4 v = *(const f32x4*)(p + 4);
  bf16x8 a;
  a[0] = (bf16)u[0]; a[1] = (bf16)u[1]; a[2] = (bf16)u[2]; a[3] = (bf16)u[3];
  a[4] = (bf16)v[0]; a[5] = (bf16)v[1]; a[6] = (bf16)v[2]; a[7] = (bf16)v[3];
  return a;
}

// ---- prep (single dispatch): blocks 0..63 pack Wp; blocks 64..67 build G2a (A_off,
//      K=128) + diag per head; blocks 68.. pack xa (4 items/thread ILP) ----
// Wp[hs][kt(8)][nt(4)][lane(64)][8]: B[k=kt*32+(lane>>4)*8+j][n=nt*16+(lane&15)]
// G2a[h][mt(7)][kt(4)][lane(64)][8]: A[row=mt*16+(l&15)][k=kt*32+(l>>4)*8+j], K=128
// xa[b][mt(7)][kt(8)][lane(64)][8]:  A[row=mt*16+(l&15)][k=kt*32+(l>>4)*8+j], rows>=98 zero
__global__ __launch_bounds__(256) void prep_kernel(const float* __restrict__ W,
                                                   bf16* __restrict__ Wp,
                                                   const float* __restrict__ e,
                                                   const int* __restrict__ cols,
                                                   half_t* __restrict__ G2a,
                                                   float* __restrict__ diagb,
                                                   const float* __restrict__ x,
                                                   bf16* __restrict__ xa, int B) {
  if (blockIdx.x < 64) {
    int t = blockIdx.x * 256 + threadIdx.x;
    int lane = t & 63;
    int nt = (t >> 6) & 3;
    int kt = (t >> 8) & 7;
    int hs = t >> 11;
    int n = nt * 16 + (lane & 15);
    int kb = kt * 32 + (lane >> 4) * 8;
    const float* src = W + (hs * CIN + kb) * HC + n;
    bf16x8 v;
#pragma unroll
    for (int j = 0; j < 8; ++j) v[j] = (bf16)src[j * HC];
    *(bf16x8*)(Wp + (long long)t * 8) = v;
    return;
  }
  if (blockIdx.x < 68) {
    // one head per block: softmax -> dense A_off [112][128] (LDS) -> frag-pack + diag
    __shared__ __align__(16) half_t g[112 * 128];  // 28672 B
    const int h = blockIdx.x - 64;
    const int tid = threadIdx.x;
    for (int i = tid; i < 112 * 128 / 2; i += 256) ((unsigned int*)g)[i] = 0u;
    __syncthreads();
    if (tid < NND) {
      const int i = tid;
      const int* cp = cols + i * KNB;
      const float* ep = e + (h * NND + i) * KNB;
      float ev[KNB];
      int cv[KNB];
      float mx = -3.0e38f;
#pragma unroll
      for (int j = 0; j < KNB; ++j) { cv[j] = cp[j]; ev[j] = ep[j]; mx = fmaxf(mx, ev[j]); }
      float s = 0.f;
#pragma unroll
      for (int j = 0; j < KNB; ++j) { ev[j] = __expf(ev[j] - mx); s += ev[j]; }
      const float inv = 1.f / s;
      float dg = 0.f;
#pragma unroll
      for (int j = 0; j < KNB; ++j) {
        float wj = ev[j] * inv;
        if (cv[j] == i) { dg = wj; wj = 0.f; }
        g[i * 128 + cv[j]] = (half_t)wj;
      }
      diagb[h * 112 + i] = dg;
    } else if (tid < 112) {
      diagb[h * 112 + tid] = 0.f;
    }
    __syncthreads();
    // frag pack: 28 (mt,kt) frags x 64 lanes, 16 B each
    for (int u = tid; u < 28 * 64; u += 256) {
      const int lane = u & 63;
      const int q = u >> 6;        // mt*4 + kt
      const int kt = q & 3;
      const int mt = q >> 2;
      const int row = mt * 16 + (lane & 15);
      const int k0 = kt * 32 + (lane >> 4) * 8;
      half8 v = *(const half8*)(g + row * 128 + k0);
      *(half8*)(G2a + (((long long)h * 28 + q) * 64 + lane) * 8) = v;
    }
    return;
  }
  // xa pack: 4 items per thread (ILP), fully-used 64B read segments, coalesced writes
  const int Bq = (B + 3) >> 2;
  int u = (blockIdx.x - 68) * 256 + threadIdx.x;
  if (u >= Bq * 7 * 8 * 64) return;
  const int lane = u & 63;
  const int kt = (u >> 6) & 7;
  const int v = u >> 9;
  const int b0 = v / 7;
  const int mt = v - b0 * 7;
  const int row = mt * 16 + (lane & 15);
  const int k0 = kt * 32 + (lane >> 4) * 8;
  bf16x8 a[4];
#pragma unroll
  for (int q = 0; q < 4; ++q) {
    const int b = b0 + Bq * q;
    a[q] = bf16x8{};
    if (b < B && row < NND) a[q] = load_a8(x + ((long long)b * NND + row) * CIN + k0);
  }
#pragma unroll
  for (int q = 0; q < 4; ++q) {
    const int b = b0 + Bq * q;
    if (b < B)
      *(bf16x8*)(xa + ((((long long)b * 7 + mt) * 8 + kt) * 64 + lane) * 8) = a[q];
  }
}

// ---- main: one block per (batch-pair, head). 512 threads = 8 waves. ----
// phase0: stage Wp-h (64KB) -> LDS, kt=0 A-frags prefetched across it.
// GEMM1 (bf16): B from LDS, A from global xa, 2-deep pipeline -> h0 (sh=0) / h1 (sh=1).
// Transpose: sh=1 waves write S = h1^T (f16, K=128 padded); sh=0 waves write
// D0T = diag[row]*h0 transposed (f32-exact scale, f16 store). Both overwrite Wp LDS.
// GEMM2 (f16): out = A_off @ h1 (K=128), A = G2a (global, wave owns mt-pair, 2-deep
// pipeline), B = S from LDS; store adds D0T + bias. 3 barriers.
__global__ __launch_bounds__(512, 4) void semgconv_kernel(
    const bf16* __restrict__ xa, const half_t* __restrict__ G2a,
    const bf16* __restrict__ Wp, const float* __restrict__ diagb,
    const float* __restrict__ bias, float* __restrict__ out, int nwg) {
  __shared__ __align__(16) unsigned char smem[65536];  // Wl, then S (34816) + D0T (30720)
  bf16* Wl = (bf16*)smem;
  half_t* S = (half_t*)smem;
  half_t* D0 = (half_t*)(smem + S_BYTES);

  const int tid = threadIdx.x;
  const int lane = tid & 63;
  const int wv = tid >> 6;

  // XCD-chunked swizzle: 4 head-blocks of each pair land on one XCD.
  int n = blockIdx.x;
  int w = ((nwg & 7) == 0) ? ((n & 7) * (nwg >> 3) + (n >> 3)) : n;
  const int bp = w >> 2;
  const int h = w & 3;
  const int b0 = bp * 2;

  const int wm = wv & 3;   // M-group: tiles {2wm, 2wm+1}; wm=3 -> tile 6 only
  const int sh = wv >> 2;  // head-half: 0 -> h0, 1 -> h1
  const int mt0 = wm * 2;
  const bool has1 = (mt0 + 1 < 7);
  const int cb = lane & 15;
  const int rsub = (lane >> 4) * 4;

  // ---- diag prefetch (used by sh=0 waves at transpose; L2-hot 1.6KB) ----
  f32x4 dg[2];
  dg[0] = *(const f32x4*)(diagb + h * 112 + mt0 * 16 + rsub);
  dg[1] = has1 ? *(const f32x4*)(diagb + h * 112 + (mt0 + 1) * 16 + rsub) : f32x4{};

  // ---- kt=0 A-frag prefetch: issued BEFORE Wp stage, completes during it ----
  const bf16* ax0 = xa + (((long long)b0 * 7 + mt0) * 8 * 64 + lane) * 8;
  const bf16* ax1 = ax0 + XA_TILE;
  bf16x8 a00 = *(const bf16x8*)(ax0);
  bf16x8 a10 = *(const bf16x8*)(ax1);
  bf16x8 a01 = {}, a11 = {};
  if (has1) {
    a01 = *(const bf16x8*)(ax0 + 4096);
    a11 = *(const bf16x8*)(ax1 + 4096);
  }

  // ---- phase 0: Wp-h -> LDS, linear 64KB copy ----
  {
    const f32x4* src = (const f32x4*)(Wp + (long long)h * 32768);
    f32x4* dst = (f32x4*)smem;
#pragma unroll
    for (int it = 0; it < 8; ++it) {
      const int idx = tid + it * 512;
      dst[idx] = src[idx];
    }
  }
  __syncthreads();  // barrier 1

  // ---- GEMM1: 2 x [112x256 bf16] @ [256x128 bf16], 2-deep A pipeline ----
  f32x4 acc[2][2][4] = {};  // [item][im][nt]
  {
    const bf16* wll = Wl + sh * 16384 + lane * 8;
#pragma unroll
    for (int kt = 0; kt < 8; ++kt) {
      bf16x8 n00, n10, n01, n11;
      if (kt < 7) {
        n00 = *(const bf16x8*)(ax0 + (kt + 1) * 512);
        n10 = *(const bf16x8*)(ax1 + (kt + 1) * 512);
        if (has1) {
          n01 = *(const bf16x8*)(ax0 + 4096 + (kt + 1) * 512);
          n11 = *(const bf16x8*)(ax1 + 4096 + (kt + 1) * 512);
        }
      }
      bf16x8 bfr[4];
#pragma unroll
      for (int nt = 0; nt < 4; ++nt)
        bfr[nt] = *(const bf16x8*)(wll + (kt * 4 + nt) * 512);
#pragma unroll
      for (int nt = 0; nt < 4; ++nt) {
        acc[0][0][nt] = __builtin_amdgcn_mfma_f32_16x16x32_bf16(a00, bfr[nt], acc[0][0][nt], 0, 0, 0);
        acc[1][0][nt] = __builtin_amdgcn_mfma_f32_16x16x32_bf16(a10, bfr[nt], acc[1][0][nt], 0, 0, 0);
      }
      if (has1) {
#pragma unroll
        for (int nt = 0; nt < 4; ++nt) {
          acc[0][1][nt] = __builtin_amdgcn_mfma_f32_16x16x32_bf16(a01, bfr[nt], acc[0][1][nt], 0, 0, 0);
          acc[1][1][nt] = __builtin_amdgcn_mfma_f32_16x16x32_bf16(a11, bfr[nt], acc[1][1][nt], 0, 0, 0);
        }
      }
      a00 = n00; a10 = n10; a01 = n01; a11 = n11;
    }
  }
  __syncthreads();  // barrier 2: Wp LDS reads done; region reusable as S + D0T

  // ---- transpose: sh=1 -> S = h1^T; sh=0 -> D0T = diag*h0 transposed ----
  if (sh) {
#pragma unroll
    for (int it2 = 0; it2 < 2; ++it2) {
#pragma unroll
      for (int im = 0; im < 2; ++im) {
        if (mt0 + im < 7) {
          const int j0 = (mt0 + im) * 16 + rsub;
#pragma unroll
          for (int nt = 0; nt < 4; ++nt) {
            half4 hv;
            hv[0] = (half_t)acc[it2][im][nt][0];
            hv[1] = (half_t)acc[it2][im][nt][1];
            hv[2] = (half_t)acc[it2][im][nt][2];
            hv[3] = (half_t)acc[it2][im][nt][3];
            *(half4*)(&S[it2 * S_HALFS + (nt * 16 + cb) * SKP + j0]) = hv;
          }
        }
      }
    }
  } else {
#pragma unroll
    for (int it2 = 0; it2 < 2; ++it2) {
#pragma unroll
      for (int im = 0; im < 2; ++im) {
        if (mt0 + im < 7) {
          const int j0 = (mt0 + im) * 16 + rsub;
#pragma unroll
          for (int nt = 0; nt < 4; ++nt) {
            half4 hv;
            hv[0] = (half_t)(dg[im][0] * acc[it2][im][nt][0]);
            hv[1] = (half_t)(dg[im][1] * acc[it2][im][nt][1]);
            hv[2] = (half_t)(dg[im][2] * acc[it2][im][nt][2]);
            hv[3] = (half_t)(dg[im][3] * acc[it2][im][nt][3]);
            *(half4*)(&D0[it2 * D0_HALFS + (nt * 16 + cb) * D0R + j0]) = hv;
          }
        }
      }
    }
  }
  // zero-pad S k=112..127 (K=128 for GEMM2)
  if (tid < 256) {
    const int it = tid >> 7;
    const int c = (tid >> 1) & 63;
    const int sg = tid & 1;
    *(half8*)(&S[it * S_HALFS + c * SKP + 112 + sg * 8]) = half8{};
  }
  __syncthreads();  // barrier 3: S + D0T ready

  // ---- GEMM2: out = A_off @ h1, K=128; wave = (item, mt-pair), 2-deep A pipeline ----
  const int it2 = wv & 1;
  const int wm2 = wv >> 1;
  const int mt0b = wm2 * 2;
  const bool has1b = (mt0b + 1 < 7);
  f32x4 a2[2][4] = {};
  {
    const half_t* g2l = G2a + ((long long)(h * 28 + mt0b * 4) * 64 + lane) * 8;
    const half_t* sl = S + it2 * S_HALFS + cb * SKP + (lane >> 4) * 8;
    half8 af0 = *(const half8*)(g2l);
    half8 af1 = {};
    if (has1b) af1 = *(const half8*)(g2l + 4 * 512);
#pragma unroll
    for (int kt = 0; kt < 4; ++kt) {
      half8 n0 = {}, n1 = {};
      if (kt < 3) {
        n0 = *(const half8*)(g2l + (kt + 1) * 512);
        if (has1b) n1 = *(const half8*)(g2l + (4 + kt + 1) * 512);
      }
      half8 bfr[4];
#pragma unroll
      for (int nt = 0; nt < 4; ++nt)
        bfr[nt] = *(const half8*)(sl + nt * 16 * SKP + kt * 32);
#pragma unroll
      for (int nt = 0; nt < 4; ++nt) {
        a2[0][nt] = __builtin_amdgcn_mfma_f32_16x16x32_f16(af0, bfr[nt], a2[0][nt], 0, 0, 0);
        if (has1b)
          a2[1][nt] = __builtin_amdgcn_mfma_f32_16x16x32_f16(af1, bfr[nt], a2[1][nt], 0, 0, 0);
      }
      af0 = n0; af1 = n1;
    }
  }

  // ---- store: + D0T (diag*h0) + bias, masked ----
  {
    float bs[4];
#pragma unroll
    for (int nt = 0; nt < 4; ++nt) bs[nt] = bias[h * HC + nt * 16 + cb];
    float* ob = out + (long long)(b0 + it2) * NND * (NH * HC) + h * HC + cb;
#pragma unroll
    for (int im = 0; im < 2; ++im) {
      const int mt = mt0b + im;
      if (mt < 7) {
#pragma unroll
        for (int nt = 0; nt < 4; ++nt) {
          half4 dv = *(const half4*)(&D0[it2 * D0_HALFS + (nt * 16 + cb) * D0R + mt * 16 + rsub]);
#pragma unroll
          for (int r = 0; r < 4; ++r) {
            const int row = mt * 16 + rsub + r;
            if (row < NND)
              ob[(long long)row * (NH * HC) + nt * 16] = a2[im][nt][r] + (float)dv[r] + bs[nt];
          }
        }
      }
    }
  }
}

extern "C" void kernel_launch(void* const* d_in, const int* in_sizes, int n_in,
                              void* d_out, int out_size, void* d_ws, size_t ws_size,
                              hipStream_t stream) {
  const float* x    = (const float*)d_in[0];
  const float* W    = (const float*)d_in[1];
  const float* e    = (const float*)d_in[2];
  const float* bias = (const float*)d_in[3];
  // d_in[4] = rows: unused (fixed pattern: row i owns edges i*K .. i*K+K-1)
  const int* cols   = (const int*)d_in[5];
  float* out        = (float*)d_out;

  int B = in_sizes[0] / (NND * CIN);  // 1024

  bf16* Wp     = (bf16*)((char*)d_ws + WP_OFF);
  half_t* G2a  = (half_t*)((char*)d_ws + G2A_OFF);
  float* diagb = (float*)((char*)d_ws + DIAG_OFF);
  bf16* xa     = (bf16*)((char*)d_ws + XA_OFF);

  const int Bq = (B + 3) >> 2;
  const int xa_blocks = (Bq * 7 * 8 * 64 + 255) / 256;
  prep_kernel<<<68 + xa_blocks, 256, 0, stream>>>(W, Wp, e, cols, G2a, diagb, x, xa, B);

  const int nwg = (B / 2) * NH;
  semgconv_kernel<<<nwg, 512, 0, stream>>>(xa, G2a, Wp, diagb, bias, out, nwg);
}

// Round 10
// 229.157 us; speedup vs baseline: 1.1012x; 1.1012x over previous
//
#include <hip/hip_runtime.h>

typedef __bf16 bf16;
typedef bf16 bf16x4 __attribute__((ext_vector_type(4)));
typedef bf16 bf16x8 __attribute__((ext_vector_type(8)));
typedef _Float16 half_t;
typedef half_t half4 __attribute__((ext_vector_type(4)));
typedef half_t half8 __attribute__((ext_vector_type(8)));
typedef float f32x4 __attribute__((ext_vector_type(4)));

#define NND 98      // landmarks
#define KNB 10      // neighbors per node
#define NH 4        // heads
#define CIN 256
#define HC 64
#define KAG 224     // aggregation GEMM K: 0..111 = h1, 112..223 = h0 (diag)
#define SROW 232    // S_T k-stride (224 + 8 pad)
#define XA_TILE (7 * 8 * 64 * 8)  // bf16 elems per batch item in xa

// workspace layout
#define WP_OFF   0
#define WP_BYTES 262144                       // 8*8*4*64*8 bf16
#define G2A_OFF  (WP_OFF + WP_BYTES)
#define G2A_BYTES (NH * 49 * 64 * 8 * 2)      // frag-packed G2, f16
#define XA_OFF   (G2A_OFF + G2A_BYTES)

__device__ __forceinline__ bf16x8 load_a8(const float* p) {
  f32x4 u = *(const f32x4*)p;
  f32x4 v = *(const f32x4*)(p + 4);
  bf16x8 a;
  a[0] = (bf16)u[0]; a[1] = (bf16)u[1]; a[2] = (bf16)u[2]; a[3] = (bf16)u[3];
  a[4] = (bf16)v[0]; a[5] = (bf16)v[1]; a[6] = (bf16)v[2]; a[7] = (bf16)v[3];
  return a;
}

// ---- prep (single dispatch): blocks 0..63 pack Wp; blocks 64..67 build G2a
//      (dense G2 in LDS -> frag pack, no HBM round-trip); blocks 68.. pack xa ----
// Wp[hs][kt(8)][nt(4)][lane(64)][8]: B[k=kt*32+(lane>>4)*8+j][n=nt*16+(lane&15)]
// G2a[h][mt(7)][kt(7)][lane(64)][8]: A[row=mt*16+(l&15)][k=kt*32+(l>>4)*8+j]
// xa[b][mt(7)][kt(8)][lane(64)][8]:  A[row=mt*16+(l&15)][k=kt*32+(l>>4)*8+j], rows>=98 zero
__global__ __launch_bounds__(256) void prep_kernel(const float* __restrict__ W,
                                                   bf16* __restrict__ Wp,
                                                   const float* __restrict__ e,
                                                   const int* __restrict__ cols,
                                                   half_t* __restrict__ G2a,
                                                   const float* __restrict__ x,
                                                   bf16* __restrict__ xa, int B) {
  if (blockIdx.x < 64) {
    int t = blockIdx.x * 256 + threadIdx.x;
    int lane = t & 63;
    int nt = (t >> 6) & 3;
    int kt = (t >> 8) & 7;
    int hs = t >> 11;
    int n = nt * 16 + (lane & 15);
    int kb = kt * 32 + (lane >> 4) * 8;
    const float* src = W + (hs * CIN + kb) * HC + n;
    bf16x8 v;
#pragma unroll
    for (int j = 0; j < 8; ++j) v[j] = (bf16)src[j * HC];
    *(bf16x8*)(Wp + (long long)t * 8) = v;
    return;
  }
  if (blockIdx.x < 68) {
    // one head per block: softmax -> dense G2 (LDS) -> frag-pack -> G2a
    __shared__ __align__(16) half_t g[112 * KAG];  // 50176 B
    const int h = blockIdx.x - 64;
    const int tid = threadIdx.x;
    for (int i = tid; i < 112 * KAG / 2; i += 256) ((unsigned int*)g)[i] = 0u;
    __syncthreads();
    if (tid < NND) {
      const int i = tid;
      const int* cp = cols + i * KNB;
      const float* ep = e + (h * NND + i) * KNB;
      float ev[KNB];
      int cv[KNB];
      float mx = -3.0e38f;
#pragma unroll
      for (int j = 0; j < KNB; ++j) { cv[j] = cp[j]; ev[j] = ep[j]; mx = fmaxf(mx, ev[j]); }
      float s = 0.f;
#pragma unroll
      for (int j = 0; j < KNB; ++j) { ev[j] = __expf(ev[j] - mx); s += ev[j]; }
      const float inv = 1.f / s;
      float dg = 0.f;
#pragma unroll
      for (int j = 0; j < KNB; ++j) {
        float wj = ev[j] * inv;
        if (cv[j] == i) { dg = wj; wj = 0.f; }
        g[i * KAG + cv[j]] = (half_t)wj;
      }
      g[i * KAG + 112 + i] = (half_t)dg;
    }
    __syncthreads();
    // frag pack: 49 (mt,kt) frags x 64 lanes, 16 B each
    for (int u = tid; u < 49 * 64; u += 256) {
      const int lane = u & 63;
      const int q = u >> 6;        // mt*7 + kt
      const int kt = q % 7;
      const int mt = q / 7;
      const int row = mt * 16 + (lane & 15);
      const int k0 = kt * 32 + (lane >> 4) * 8;
      half8 v = *(const half8*)(g + row * KAG + k0);
      *(half8*)(G2a + (((long long)h * 49 + q) * 64 + lane) * 8) = v;
    }
    return;
  }
  // xa pack: 4 items per thread (ILP), coalesced 128B/row reads, coalesced frag writes
  const int Bq = (B + 3) >> 2;
  int u = (blockIdx.x - 68) * 256 + threadIdx.x;
  if (u >= Bq * 7 * 8 * 64) return;
  const int lane = u & 63;
  const int kt = (u >> 6) & 7;
  const int v = u >> 9;
  const int b0 = v / 7;
  const int mt = v - b0 * 7;
  const int row = mt * 16 + (lane & 15);
  const int k0 = kt * 32 + (lane >> 4) * 8;
  bf16x8 a[4];
#pragma unroll
  for (int q = 0; q < 4; ++q) {
    const int b = b0 + Bq * q;
    a[q] = bf16x8{};
    if (b < B && row < NND) a[q] = load_a8(x + ((long long)b * NND + row) * CIN + k0);
  }
#pragma unroll
  for (int q = 0; q < 4; ++q) {
    const int b = b0 + Bq * q;
    if (b < B)
      *(bf16x8*)(xa + ((((long long)b * 7 + mt) * 8 + kt) * 64 + lane) * 8) = a[q];
  }
}

// ---- main: one block per (batch-pair, head). 512 threads = 8 waves. ----
// phase0: stage Wp-h (64KB) -> LDS (linear), with kt=0 A-frags prefetched across it.
// GEMM1 (bf16): B from LDS, A from global xa, 2-deep software pipeline on A.
// S_T (f16) overwrites the Wp LDS region. GEMM2 (f16): A = G2a (global, wave owns
// mt-pair, 2-deep pipeline; entry frags + bias prefetched ACROSS barrier 3),
// B = S from LDS. 3 barriers.
__global__ __launch_bounds__(512, 4) void semgconv_kernel(
    const bf16* __restrict__ xa, const half_t* __restrict__ G2a,
    const bf16* __restrict__ Wp, const float* __restrict__ bias,
    float* __restrict__ out, int nwg) {
  __shared__ __align__(16) unsigned char smem[65536];  // Wp-h stage, then S[2][64*SROW]
  bf16* Wl = (bf16*)smem;
  half_t* S = (half_t*)smem;

  const int tid = threadIdx.x;
  const int lane = tid & 63;
  const int wv = tid >> 6;

  // XCD-chunked swizzle: 4 head-blocks of each pair land on one XCD.
  int n = blockIdx.x;
  int w = ((nwg & 7) == 0) ? ((n & 7) * (nwg >> 3) + (n >> 3)) : n;
  const int bp = w >> 2;
  const int h = w & 3;
  const int b0 = bp * 2;

  const int wm = wv & 3;   // M-group: tiles {2wm, 2wm+1}; wm=3 -> tile 6 only
  const int sh = wv >> 2;  // head-half: 0 -> h0, 1 -> h1
  const int mt0 = wm * 2;
  const bool has1 = (mt0 + 1 < 7);
  const int cb = lane & 15;

  // ---- kt=0 A-frag prefetch: issued BEFORE Wp stage, completes during it ----
  const bf16* ax0 = xa + (((long long)b0 * 7 + mt0) * 8 * 64 + lane) * 8;
  const bf16* ax1 = ax0 + XA_TILE;
  bf16x8 a00 = *(const bf16x8*)(ax0);
  bf16x8 a10 = *(const bf16x8*)(ax1);
  bf16x8 a01 = {}, a11 = {};
  if (has1) {
    a01 = *(const bf16x8*)(ax0 + 4096);
    a11 = *(const bf16x8*)(ax1 + 4096);
  }

  // ---- phase 0: Wp-h -> LDS, linear 64KB copy (coalesced 16B/lane) ----
  {
    const f32x4* src = (const f32x4*)(Wp + (long long)h * 32768);
    f32x4* dst = (f32x4*)smem;
#pragma unroll
    for (int it = 0; it < 8; ++it) {
      const int idx = tid + it * 512;
      dst[idx] = src[idx];
    }
  }
  __syncthreads();  // barrier 1: Wp-h in LDS (also drains A prefetch)

  // ---- GEMM1: 2 x [112x256 bf16] @ [256x128 bf16], 2-deep A pipeline ----
  f32x4 acc[2][2][4] = {};  // [item][im][nt]
  {
    const bf16* wll = Wl + sh * 16384 + lane * 8;
#pragma unroll
    for (int kt = 0; kt < 8; ++kt) {
      bf16x8 n00, n10, n01, n11;
      if (kt < 7) {  // issue kt+1 loads before consuming kt
        n00 = *(const bf16x8*)(ax0 + (kt + 1) * 512);
        n10 = *(const bf16x8*)(ax1 + (kt + 1) * 512);
        if (has1) {
          n01 = *(const bf16x8*)(ax0 + 4096 + (kt + 1) * 512);
          n11 = *(const bf16x8*)(ax1 + 4096 + (kt + 1) * 512);
        }
      }
      bf16x8 bfr[4];
#pragma unroll
      for (int nt = 0; nt < 4; ++nt)
        bfr[nt] = *(const bf16x8*)(wll + (kt * 4 + nt) * 512);  // conflict-free b128
#pragma unroll
      for (int nt = 0; nt < 4; ++nt) {
        acc[0][0][nt] = __builtin_amdgcn_mfma_f32_16x16x32_bf16(a00, bfr[nt], acc[0][0][nt], 0, 0, 0);
        acc[1][0][nt] = __builtin_amdgcn_mfma_f32_16x16x32_bf16(a10, bfr[nt], acc[1][0][nt], 0, 0, 0);
      }
      if (has1) {
#pragma unroll
        for (int nt = 0; nt < 4; ++nt) {
          acc[0][1][nt] = __builtin_amdgcn_mfma_f32_16x16x32_bf16(a01, bfr[nt], acc[0][1][nt], 0, 0, 0);
          acc[1][1][nt] = __builtin_amdgcn_mfma_f32_16x16x32_bf16(a11, bfr[nt], acc[1][1][nt], 0, 0, 0);
        }
      }
      a00 = n00; a10 = n10; a01 = n01; a11 = n11;
    }
  }
  __syncthreads();  // barrier 2: all Wp LDS reads done; region reusable as S

  // ---- acc -> S_T: S[it][col*SROW + k], k = row (h1, sh=1) or 112+row (h0, sh=0) ----
  {
    const int jb = (sh ? 0 : 112) + (lane >> 4) * 4;
#pragma unroll
    for (int it2 = 0; it2 < 2; ++it2) {
#pragma unroll
      for (int im = 0; im < 2; ++im) {
        if (mt0 + im < 7) {
          const int j0 = jb + (mt0 + im) * 16;
#pragma unroll
          for (int nt = 0; nt < 4; ++nt) {
            half4 hv;
            hv[0] = (half_t)acc[it2][im][nt][0];
            hv[1] = (half_t)acc[it2][im][nt][1];
            hv[2] = (half_t)acc[it2][im][nt][2];
            hv[3] = (half_t)acc[it2][im][nt][3];
            *(half4*)(&S[it2 * (64 * SROW) + (nt * 16 + cb) * SROW + j0]) = hv;
          }
        }
      }
    }
  }

  // ---- GEMM2 entry prefetch: issued BEFORE barrier 3, completes during its drain ----
  const int it2 = wv & 1;
  const int wm2 = wv >> 1;
  const int mt0b = wm2 * 2;      // mt pair {mt0b, mt0b+1}; wm2=3 -> mt 6 only
  const bool has1b = (mt0b + 1 < 7);
  const half_t* g2l = G2a + ((long long)(h * 49 + mt0b * 7) * 64 + lane) * 8;
  half8 af0 = *(const half8*)(g2l);
  half8 af1 = {};
  if (has1b) af1 = *(const half8*)(g2l + 7 * 512);
  float bs[4];
#pragma unroll
  for (int nt = 0; nt < 4; ++nt) bs[nt] = bias[h * HC + nt * 16 + cb];

  __syncthreads();  // barrier 3: S ready (G2a/bias prefetch drained here too)

  // ---- GEMM2: wave = (item, mt-pair), 2-deep G2a pipeline ----
  f32x4 a2[2][4] = {};
  {
    const half_t* sl = S + it2 * (64 * SROW) + cb * SROW + (lane >> 4) * 8;
#pragma unroll
    for (int kt = 0; kt < 7; ++kt) {
      half8 n0, n1;
      if (kt < 6) {
        n0 = *(const half8*)(g2l + (long long)(kt + 1) * 512);
        if (has1b) n1 = *(const half8*)(g2l + (long long)(8 + kt) * 512);
      }
      half8 bfr[4];
#pragma unroll
      for (int nt = 0; nt < 4; ++nt)
        bfr[nt] = *(const half8*)(sl + nt * 16 * SROW + kt * 32);
#pragma unroll
      for (int nt = 0; nt < 4; ++nt) {
        a2[0][nt] = __builtin_amdgcn_mfma_f32_16x16x32_f16(af0, bfr[nt], a2[0][nt], 0, 0, 0);
        if (has1b)
          a2[1][nt] = __builtin_amdgcn_mfma_f32_16x16x32_f16(af1, bfr[nt], a2[1][nt], 0, 0, 0);
      }
      af0 = n0; af1 = n1;
    }
  }

  // ---- bias + masked store ----
  {
    const int r0 = (lane >> 4) * 4;
    float* ob = out + (long long)(b0 + it2) * NND * (NH * HC) + h * HC + cb;
#pragma unroll
    for (int im = 0; im < 2; ++im) {
      const int mt = mt0b + im;
      if (mt < 7) {
#pragma unroll
        for (int r = 0; r < 4; ++r) {
          const int row = mt * 16 + r0 + r;
          if (row < NND) {
#pragma unroll
            for (int nt = 0; nt < 4; ++nt)
              ob[(long long)row * (NH * HC) + nt * 16] = a2[im][nt][r] + bs[nt];
          }
        }
      }
    }
  }
}

extern "C" void kernel_launch(void* const* d_in, const int* in_sizes, int n_in,
                              void* d_out, int out_size, void* d_ws, size_t ws_size,
                              hipStream_t stream) {
  const float* x    = (const float*)d_in[0];
  const float* W    = (const float*)d_in[1];
  const float* e    = (const float*)d_in[2];
  const float* bias = (const float*)d_in[3];
  // d_in[4] = rows: unused (fixed pattern: row i owns edges i*K .. i*K+K-1)
  const int* cols   = (const int*)d_in[5];
  float* out        = (float*)d_out;

  int B = in_sizes[0] / (NND * CIN);  // 1024

  bf16* Wp    = (bf16*)((char*)d_ws + WP_OFF);
  half_t* G2a = (half_t*)((char*)d_ws + G2A_OFF);
  bf16* xa    = (bf16*)((char*)d_ws + XA_OFF);

  const int Bq = (B + 3) >> 2;
  const int xa_blocks = (Bq * 7 * 8 * 64 + 255) / 256;
  prep_kernel<<<68 + xa_blocks, 256, 0, stream>>>(W, Wp, e, cols, G2a, x, xa, B);

  const int nwg = (B / 2) * NH;
  semgconv_kernel<<<nwg, 512, 0, stream>>>(xa, G2a, Wp, bias, out, nwg);
}

// Round 11
// 225.568 us; speedup vs baseline: 1.1187x; 1.0159x over previous
//
#include <hip/hip_runtime.h>

typedef __bf16 bf16;
typedef bf16 bf16x4 __attribute__((ext_vector_type(4)));
typedef bf16 bf16x8 __attribute__((ext_vector_type(8)));
typedef _Float16 half_t;
typedef half_t half4 __attribute__((ext_vector_type(4)));
typedef half_t half8 __attribute__((ext_vector_type(8)));
typedef float f32x4 __attribute__((ext_vector_type(4)));

#define NND 98      // landmarks
#define KNB 10      // neighbors per node
#define NH 4        // heads
#define CIN 256
#define HC 64
#define KAG 224     // aggregation GEMM K: 0..111 = h1, 112..223 = h0 (diag)
#define SROW 232    // S_T k-stride (224 + 8 pad)
#define XA_TILE (7 * 8 * 64 * 8)  // bf16 elems per batch item in xa

// workspace layout
#define WP_OFF   0
#define WP_BYTES 262144                       // 8*8*4*64*8 bf16
#define G2A_OFF  (WP_OFF + WP_BYTES)
#define G2A_BYTES (NH * 49 * 64 * 8 * 2)      // frag-packed G2, f16
#define XA_OFF   (G2A_OFF + G2A_BYTES)

__device__ __forceinline__ bf16x8 load_a8(const float* p) {
  f32x4 u = *(const f32x4*)p;
  f32x4 v = *(const f32x4*)(p + 4);
  bf16x8 a;
  a[0] = (bf16)u[0]; a[1] = (bf16)u[1]; a[2] = (bf16)u[2]; a[3] = (bf16)u[3];
  a[4] = (bf16)v[0]; a[5] = (bf16)v[1]; a[6] = (bf16)v[2]; a[7] = (bf16)v[3];
  return a;
}

// ---- prep (single dispatch): blocks 0..63 pack Wp; blocks 64..67 build G2a
//      (dense G2 in LDS -> frag pack, no HBM round-trip); blocks 68.. pack xa ----
// Wp[hs][kt(8)][nt(4)][lane(64)][8]: B[k=kt*32+(lane>>4)*8+j][n=nt*16+(lane&15)]
// G2a[h][mt(7)][kt(7)][lane(64)][8]: A[row=mt*16+(l&15)][k=kt*32+(l>>4)*8+j]
// xa[b][mt(7)][kt(8)][lane(64)][8]:  A[row=mt*16+(l&15)][k=kt*32+(l>>4)*8+j], rows>=98 zero
__global__ __launch_bounds__(256) void prep_kernel(const float* __restrict__ W,
                                                   bf16* __restrict__ Wp,
                                                   const float* __restrict__ e,
                                                   const int* __restrict__ cols,
                                                   half_t* __restrict__ G2a,
                                                   const float* __restrict__ x,
                                                   bf16* __restrict__ xa, int B) {
  if (blockIdx.x < 64) {
    int t = blockIdx.x * 256 + threadIdx.x;
    int lane = t & 63;
    int nt = (t >> 6) & 3;
    int kt = (t >> 8) & 7;
    int hs = t >> 11;
    int n = nt * 16 + (lane & 15);
    int kb = kt * 32 + (lane >> 4) * 8;
    const float* src = W + (hs * CIN + kb) * HC + n;
    bf16x8 v;
#pragma unroll
    for (int j = 0; j < 8; ++j) v[j] = (bf16)src[j * HC];
    *(bf16x8*)(Wp + (long long)t * 8) = v;
    return;
  }
  if (blockIdx.x < 68) {
    // one head per block: softmax -> dense G2 (LDS) -> frag-pack -> G2a
    __shared__ __align__(16) half_t g[112 * KAG];  // 50176 B
    const int h = blockIdx.x - 64;
    const int tid = threadIdx.x;
    for (int i = tid; i < 112 * KAG / 2; i += 256) ((unsigned int*)g)[i] = 0u;
    __syncthreads();
    if (tid < NND) {
      const int i = tid;
      const int* cp = cols + i * KNB;
      const float* ep = e + (h * NND + i) * KNB;
      float ev[KNB];
      int cv[KNB];
      float mx = -3.0e38f;
#pragma unroll
      for (int j = 0; j < KNB; ++j) { cv[j] = cp[j]; ev[j] = ep[j]; mx = fmaxf(mx, ev[j]); }
      float s = 0.f;
#pragma unroll
      for (int j = 0; j < KNB; ++j) { ev[j] = __expf(ev[j] - mx); s += ev[j]; }
      const float inv = 1.f / s;
      float dg = 0.f;
#pragma unroll
      for (int j = 0; j < KNB; ++j) {
        float wj = ev[j] * inv;
        if (cv[j] == i) { dg = wj; wj = 0.f; }
        g[i * KAG + cv[j]] = (half_t)wj;
      }
      g[i * KAG + 112 + i] = (half_t)dg;
    }
    __syncthreads();
    // frag pack: 49 (mt,kt) frags x 64 lanes, 16 B each
    for (int u = tid; u < 49 * 64; u += 256) {
      const int lane = u & 63;
      const int q = u >> 6;        // mt*7 + kt
      const int kt = q % 7;
      const int mt = q / 7;
      const int row = mt * 16 + (lane & 15);
      const int k0 = kt * 32 + (lane >> 4) * 8;
      half8 v = *(const half8*)(g + row * KAG + k0);
      *(half8*)(G2a + (((long long)h * 49 + q) * 64 + lane) * 8) = v;
    }
    return;
  }
  // xa pack: 4 items per thread (ILP), coalesced 128B/row reads, coalesced frag writes
  const int Bq = (B + 3) >> 2;
  int u = (blockIdx.x - 68) * 256 + threadIdx.x;
  if (u >= Bq * 7 * 8 * 64) return;
  const int lane = u & 63;
  const int kt = (u >> 6) & 7;
  const int v = u >> 9;
  const int b0 = v / 7;
  const int mt = v - b0 * 7;
  const int row = mt * 16 + (lane & 15);
  const int k0 = kt * 32 + (lane >> 4) * 8;
  bf16x8 a[4];
#pragma unroll
  for (int q = 0; q < 4; ++q) {
    const int b = b0 + Bq * q;
    a[q] = bf16x8{};
    if (b < B && row < NND) a[q] = load_a8(x + ((long long)b * NND + row) * CIN + k0);
  }
#pragma unroll
  for (int q = 0; q < 4; ++q) {
    const int b = b0 + Bq * q;
    if (b < B)
      *(bf16x8*)(xa + ((((long long)b * 7 + mt) * 8 + kt) * 64 + lane) * 8) = a[q];
  }
}

// ---- main: one block per (batch-pair, head). 512 threads = 8 waves. ----
// phase0: stage Wp-h (64KB) -> LDS via async global_load_lds (16B/lane, linear dest),
// with kt=0 A-frags prefetched ahead of it; barrier 1 drains both.
// GEMM1 (bf16): B from LDS, A from global xa, 2-deep software pipeline on A.
// S_T (f16) overwrites the Wp LDS region. GEMM2 (f16): A = G2a (global, wave owns
// mt-pair, 2-deep pipeline; entry frags + bias prefetched ACROSS barrier 3),
// B = S from LDS. 3 barriers.
__global__ __launch_bounds__(512, 4) void semgconv_kernel(
    const bf16* __restrict__ xa, const half_t* __restrict__ G2a,
    const bf16* __restrict__ Wp, const float* __restrict__ bias,
    float* __restrict__ out, int nwg) {
  __shared__ __align__(16) unsigned char smem[65536];  // Wp-h stage, then S[2][64*SROW]
  bf16* Wl = (bf16*)smem;
  half_t* S = (half_t*)smem;

  const int tid = threadIdx.x;
  const int lane = tid & 63;
  const int wv = tid >> 6;

  // XCD-chunked swizzle: 4 head-blocks of each pair land on one XCD.
  int n = blockIdx.x;
  int w = ((nwg & 7) == 0) ? ((n & 7) * (nwg >> 3) + (n >> 3)) : n;
  const int bp = w >> 2;
  const int h = w & 3;
  const int b0 = bp * 2;

  const int wm = wv & 3;   // M-group: tiles {2wm, 2wm+1}; wm=3 -> tile 6 only
  const int sh = wv >> 2;  // head-half: 0 -> h0, 1 -> h1
  const int mt0 = wm * 2;
  const bool has1 = (mt0 + 1 < 7);
  const int cb = lane & 15;

  // ---- kt=0 A-frag prefetch: issued BEFORE Wp stage, completes during it ----
  const bf16* ax0 = xa + (((long long)b0 * 7 + mt0) * 8 * 64 + lane) * 8;
  const bf16* ax1 = ax0 + XA_TILE;
  bf16x8 a00 = *(const bf16x8*)(ax0);
  bf16x8 a10 = *(const bf16x8*)(ax1);
  bf16x8 a01 = {}, a11 = {};
  if (has1) {
    a01 = *(const bf16x8*)(ax0 + 4096);
    a11 = *(const bf16x8*)(ax1 + 4096);
  }

  // ---- phase 0: Wp-h -> LDS via async DMA (no VGPR round-trip) ----
  // Per wave-iter: one global_load_lds_dwordx4 moves 64 lanes x 16B = 1KB to the
  // wave's linear LDS chunk (dest = uniform base + lane*16, exactly HW contract).
  {
    const unsigned char* srcb = (const unsigned char*)(Wp + (long long)h * 32768);
#pragma unroll
    for (int it = 0; it < 8; ++it) {
      const int base = (it * 512 + wv * 64) * 16;  // byte offset of wave's 1KB chunk
      __builtin_amdgcn_global_load_lds(
          (const __attribute__((address_space(1))) unsigned int*)(srcb + base + lane * 16),
          (__attribute__((address_space(3))) unsigned int*)(smem + base),
          16, 0, 0);
    }
  }
  __syncthreads();  // barrier 1: Wp-h in LDS (drains DMA + A prefetch)

  // ---- GEMM1: 2 x [112x256 bf16] @ [256x128 bf16], 2-deep A pipeline ----
  f32x4 acc[2][2][4] = {};  // [item][im][nt]
  {
    const bf16* wll = Wl + sh * 16384 + lane * 8;
#pragma unroll
    for (int kt = 0; kt < 8; ++kt) {
      bf16x8 n00, n10, n01, n11;
      if (kt < 7) {  // issue kt+1 loads before consuming kt
        n00 = *(const bf16x8*)(ax0 + (kt + 1) * 512);
        n10 = *(const bf16x8*)(ax1 + (kt + 1) * 512);
        if (has1) {
          n01 = *(const bf16x8*)(ax0 + 4096 + (kt + 1) * 512);
          n11 = *(const bf16x8*)(ax1 + 4096 + (kt + 1) * 512);
        }
      }
      bf16x8 bfr[4];
#pragma unroll
      for (int nt = 0; nt < 4; ++nt)
        bfr[nt] = *(const bf16x8*)(wll + (kt * 4 + nt) * 512);  // conflict-free b128
#pragma unroll
      for (int nt = 0; nt < 4; ++nt) {
        acc[0][0][nt] = __builtin_amdgcn_mfma_f32_16x16x32_bf16(a00, bfr[nt], acc[0][0][nt], 0, 0, 0);
        acc[1][0][nt] = __builtin_amdgcn_mfma_f32_16x16x32_bf16(a10, bfr[nt], acc[1][0][nt], 0, 0, 0);
      }
      if (has1) {
#pragma unroll
        for (int nt = 0; nt < 4; ++nt) {
          acc[0][1][nt] = __builtin_amdgcn_mfma_f32_16x16x32_bf16(a01, bfr[nt], acc[0][1][nt], 0, 0, 0);
          acc[1][1][nt] = __builtin_amdgcn_mfma_f32_16x16x32_bf16(a11, bfr[nt], acc[1][1][nt], 0, 0, 0);
        }
      }
      a00 = n00; a10 = n10; a01 = n01; a11 = n11;
    }
  }
  __syncthreads();  // barrier 2: all Wp LDS reads done; region reusable as S

  // ---- acc -> S_T: S[it][col*SROW + k], k = row (h1, sh=1) or 112+row (h0, sh=0) ----
  {
    const int jb = (sh ? 0 : 112) + (lane >> 4) * 4;
#pragma unroll
    for (int it2 = 0; it2 < 2; ++it2) {
#pragma unroll
      for (int im = 0; im < 2; ++im) {
        if (mt0 + im < 7) {
          const int j0 = jb + (mt0 + im) * 16;
#pragma unroll
          for (int nt = 0; nt < 4; ++nt) {
            half4 hv;
            hv[0] = (half_t)acc[it2][im][nt][0];
            hv[1] = (half_t)acc[it2][im][nt][1];
            hv[2] = (half_t)acc[it2][im][nt][2];
            hv[3] = (half_t)acc[it2][im][nt][3];
            *(half4*)(&S[it2 * (64 * SROW) + (nt * 16 + cb) * SROW + j0]) = hv;
          }
        }
      }
    }
  }

  // ---- GEMM2 entry prefetch: issued BEFORE barrier 3, completes during its drain ----
  const int it2 = wv & 1;
  const int wm2 = wv >> 1;
  const int mt0b = wm2 * 2;      // mt pair {mt0b, mt0b+1}; wm2=3 -> mt 6 only
  const bool has1b = (mt0b + 1 < 7);
  const half_t* g2l = G2a + ((long long)(h * 49 + mt0b * 7) * 64 + lane) * 8;
  half8 af0 = *(const half8*)(g2l);
  half8 af1 = {};
  if (has1b) af1 = *(const half8*)(g2l + 7 * 512);
  float bs[4];
#pragma unroll
  for (int nt = 0; nt < 4; ++nt) bs[nt] = bias[h * HC + nt * 16 + cb];

  __syncthreads();  // barrier 3: S ready (G2a/bias prefetch drained here too)

  // ---- GEMM2: wave = (item, mt-pair), 2-deep G2a pipeline ----
  f32x4 a2[2][4] = {};
  {
    const half_t* sl = S + it2 * (64 * SROW) + cb * SROW + (lane >> 4) * 8;
#pragma unroll
    for (int kt = 0; kt < 7; ++kt) {
      half8 n0, n1;
      if (kt < 6) {
        n0 = *(const half8*)(g2l + (long long)(kt + 1) * 512);
        if (has1b) n1 = *(const half8*)(g2l + (long long)(8 + kt) * 512);
      }
      half8 bfr[4];
#pragma unroll
      for (int nt = 0; nt < 4; ++nt)
        bfr[nt] = *(const half8*)(sl + nt * 16 * SROW + kt * 32);
#pragma unroll
      for (int nt = 0; nt < 4; ++nt) {
        a2[0][nt] = __builtin_amdgcn_mfma_f32_16x16x32_f16(af0, bfr[nt], a2[0][nt], 0, 0, 0);
        if (has1b)
          a2[1][nt] = __builtin_amdgcn_mfma_f32_16x16x32_f16(af1, bfr[nt], a2[1][nt], 0, 0, 0);
      }
      af0 = n0; af1 = n1;
    }
  }

  // ---- bias + masked store ----
  {
    const int r0 = (lane >> 4) * 4;
    float* ob = out + (long long)(b0 + it2) * NND * (NH * HC) + h * HC + cb;
#pragma unroll
    for (int im = 0; im < 2; ++im) {
      const int mt = mt0b + im;
      if (mt < 7) {
#pragma unroll
        for (int r = 0; r < 4; ++r) {
          const int row = mt * 16 + r0 + r;
          if (row < NND) {
#pragma unroll
            for (int nt = 0; nt < 4; ++nt)
              ob[(long long)row * (NH * HC) + nt * 16] = a2[im][nt][r] + bs[nt];
          }
        }
      }
    }
  }
}

extern "C" void kernel_launch(void* const* d_in, const int* in_sizes, int n_in,
                              void* d_out, int out_size, void* d_ws, size_t ws_size,
                              hipStream_t stream) {
  const float* x    = (const float*)d_in[0];
  const float* W    = (const float*)d_in[1];
  const float* e    = (const float*)d_in[2];
  const float* bias = (const float*)d_in[3];
  // d_in[4] = rows: unused (fixed pattern: row i owns edges i*K .. i*K+K-1)
  const int* cols   = (const int*)d_in[5];
  float* out        = (float*)d_out;

  int B = in_sizes[0] / (NND * CIN);  // 1024

  bf16* Wp    = (bf16*)((char*)d_ws + WP_OFF);
  half_t* G2a = (half_t*)((char*)d_ws + G2A_OFF);
  bf16* xa    = (bf16*)((char*)d_ws + XA_OFF);

  const int Bq = (B + 3) >> 2;
  const int xa_blocks = (Bq * 7 * 8 * 64 + 255) / 256;
  prep_kernel<<<68 + xa_blocks, 256, 0, stream>>>(W, Wp, e, cols, G2a, x, xa, B);

  const int nwg = (B / 2) * NH;
  semgconv_kernel<<<nwg, 512, 0, stream>>>(xa, G2a, Wp, bias, out, nwg);
}